// Round 1
// baseline (917.646 us; speedup 1.0000x reference)
//
#include <hip/hip_runtime.h>

#define HH 128
#define GG 512
#define BN 32
#define KB 16
#define NT 256

__device__ __forceinline__ float sigf(float x){
  x = fminf(fmaxf(x, -30.f), 30.f);
  return 1.f/(1.f + __expf(-x));
}
__device__ __forceinline__ float tanhf_(float x){
  x = fminf(fmaxf(x, -15.f), 15.f);
  float e = __expf(2.f*x);
  return (e - 1.f)/(e + 1.f);
}

// Fold W (512x256 row-major) into transposed effective weights:
//  WTe[k][g] = W[g][k] + 0.5*W[g][128+k]   (internal nodes: x = 0.5*ch_sum)
//  WTl[k][g] = W[g][128+k]                  (leaf: ch_sum = 0)
__global__ void prep_kernel(const float* __restrict__ W,
                            float* __restrict__ WTe, float* __restrict__ WTl){
  int idx = blockIdx.x*NT + threadIdx.x;   // 0..65535
  int k = idx & 127;
  int g = idx >> 7;
  float w0 = W[g*256 + k];
  float w1 = W[g*256 + 128 + k];
  WTe[k*GG + g] = w0 + 0.5f*w1;
  WTl[k*GG + g] = w1;
}

// One tree level: gates[N,512] = A[N,128] @ WT[128,512]; LSTM cell epilogue.
// LEAF=1: A = x_leaf rows, cc = 0.  LEAF=0: A = h[2J]+h[2J+1], cc = c[2J]+c[2J+1].
template<int LEAF>
__global__ __launch_bounds__(NT) void level_kernel(
    const float* __restrict__ h_prev, const float* __restrict__ c_prev,
    const float* __restrict__ x_leaf,
    const float* __restrict__ WT, const float* __restrict__ bias,
    float* __restrict__ h_out, float* __restrict__ c_out, int N)
{
  __shared__ float AsT[HH][BN+4];   // transposed A tile, padded stride 36
  __shared__ float Ws[KB][GG];      // K-chunk of weights, 32KB

  const int t = threadIdx.x;

  // ---- stage A (transposed into LDS) ----
  {
    int n  = t >> 3;        // 0..31 node within block
    int l8 = t & 7;
    int J  = blockIdx.x*BN + n;
    bool valid = (J < N);
#pragma unroll
    for (int rr = 0; rr < 4; ++rr){
      int k = l8*4 + rr*32;
      float v[4] = {0.f,0.f,0.f,0.f};
      if (valid){
        if (LEAF){
          *(float4*)v = *(const float4*)&x_leaf[J*HH + k];
        } else {
          float a0[4], a1[4];
          *(float4*)a0 = *(const float4*)&h_prev[(2*J)*HH + k];
          *(float4*)a1 = *(const float4*)&h_prev[(2*J+1)*HH + k];
#pragma unroll
          for (int e=0;e<4;++e) v[e] = a0[e] + a1[e];
        }
      }
#pragma unroll
      for (int e=0;e<4;++e) AsT[k+e][n] = v[e];
    }
  }

  const int tg = t & 31, tn = t >> 5;
  const int j0 = tg*4;    // feature base (0..124)
  const int n0 = tn*4;    // node base within block (0..28)

  float acc[4][4][4];     // [node r][feature d][gate type q]
#pragma unroll
  for (int r=0;r<4;++r)
#pragma unroll
    for (int d=0;d<4;++d)
#pragma unroll
      for (int q=0;q<4;++q) acc[r][d][q] = 0.f;

  for (int kc = 0; kc < HH/KB; ++kc){
    // stage W chunk: KB*GG/4 = 2048 float4, 8 per thread, coalesced
#pragma unroll
    for (int i = 0; i < (KB*GG/4)/NT; ++i){
      int f4 = t + i*NT;
      int kk = f4 >> 7;
      int gg = (f4 & 127)*4;
      *(float4*)&Ws[kk][gg] = *(const float4*)&WT[(kc*KB+kk)*GG + gg];
    }
    __syncthreads();
#pragma unroll
    for (int kk=0; kk<KB; ++kk){
      int k = kc*KB + kk;
      float a[4];
      *(float4*)a = *(const float4*)&AsT[k][n0];
      const float* wr = &Ws[kk][0];
      float w0[4], w1[4], w2[4], w3[4];
      *(float4*)w0 = *(const float4*)&wr[j0];
      *(float4*)w1 = *(const float4*)&wr[j0+128];
      *(float4*)w2 = *(const float4*)&wr[j0+256];
      *(float4*)w3 = *(const float4*)&wr[j0+384];
#pragma unroll
      for (int r=0;r<4;++r){
#pragma unroll
        for (int d=0;d<4;++d){
          acc[r][d][0] += a[r]*w0[d];
          acc[r][d][1] += a[r]*w1[d];
          acc[r][d][2] += a[r]*w2[d];
          acc[r][d][3] += a[r]*w3[d];
        }
      }
    }
    __syncthreads();
  }

  // ---- epilogue: LSTM cell, all gate types in-register ----
  float Bf[4], Bi[4], Bg[4], Bo[4];
  *(float4*)Bf = *(const float4*)&bias[j0];
  *(float4*)Bi = *(const float4*)&bias[HH + j0];
  *(float4*)Bg = *(const float4*)&bias[2*HH + j0];
  *(float4*)Bo = *(const float4*)&bias[3*HH + j0];

#pragma unroll
  for (int r=0;r<4;++r){
    int J = blockIdx.x*BN + n0 + r;
    if (J >= N) continue;
    float CC[4] = {0.f,0.f,0.f,0.f};
    if (!LEAF){
      float c0[4], c1[4];
      *(float4*)c0 = *(const float4*)&c_prev[(2*J)*HH + j0];
      *(float4*)c1 = *(const float4*)&c_prev[(2*J+1)*HH + j0];
#pragma unroll
      for (int e=0;e<4;++e) CC[e] = c0[e] + c1[e];
    }
    float hv[4], cv[4];
#pragma unroll
    for (int d=0; d<4; ++d){
      float f = acc[r][d][0] + Bf[d];
      float i = acc[r][d][1] + Bi[d];
      float g = acc[r][d][2] + Bg[d];
      float o = acc[r][d][3] + Bo[d];
      float c = sigf(f)*CC[d] + sigf(i)*tanhf_(g);
      float h = sigf(o)*tanhf_(c);
      cv[d] = c; hv[d] = h;
    }
    *(float4*)&h_out[J*HH + j0] = *(float4*)hv;
    *(float4*)&c_out[J*HH + j0] = *(float4*)cv;
  }
}

extern "C" void kernel_launch(void* const* d_in, const int* in_sizes, int n_in,
                              void* d_out, int out_size, void* d_ws, size_t ws_size,
                              hipStream_t stream){
  const float* leaf = (const float*)d_in[0];   // 131072 x 128 f32
  const float* W    = (const float*)d_in[1];   // 512 x 256 f32
  const float* bias = (const float*)d_in[2];   // 512 f32
  float* out = (float*)d_out;                  // 128 f32
  float* ws  = (float*)d_ws;

  // workspace layout (floats)
  float* WTe = ws;                       // 128*512
  float* WTl = ws + 65536;               // 128*512
  float* hA  = ws + 131072;              // 131072*128
  float* cA  = hA + (1<<17)*HH;          // 131072*128
  float* hB  = cA + (1<<17)*HH;          // 65536*128
  float* cB  = hB + (1<<16)*HH;          // 65536*128
  // total ~201.9 MB

  prep_kernel<<<(GG*HH)/NT, NT, 0, stream>>>(W, WTe, WTl);

  int N = 1<<17;
  level_kernel<1><<<N/BN, NT, 0, stream>>>(nullptr, nullptr, leaf, WTl, bias, hA, cA, N);

  float *hin=hA, *cin=cA, *hout=hB, *cout=cB;
  for (int l = 1; l <= 17; ++l){
    N >>= 1;
    float* ho = (N==1) ? out : hout;
    int grid = (N + BN - 1)/BN;
    level_kernel<0><<<grid, NT, 0, stream>>>(hin, cin, nullptr, WTe, bias, ho, cout, N);
    float* th=hin; hin=hout; hout=th;
    float* tc=cin; cin=cout; cout=tc;
  }
  (void)in_sizes; (void)n_in; (void)out_size; (void)ws_size;
}

// Round 2
// 356.410 us; speedup vs baseline: 2.5747x; 2.5747x over previous
//
#include <hip/hip_runtime.h>

#define HH 128
#define GG 512
#define BN 32
#define NT 256

typedef float  f32x4  __attribute__((ext_vector_type(4)));
typedef short  bf16x8 __attribute__((ext_vector_type(8)));

static __device__ __forceinline__ unsigned short bf16_rne(float f){
  unsigned int u = __float_as_uint(f);
  unsigned int r = u + 0x7fffu + ((u >> 16) & 1u);
  return (unsigned short)(r >> 16);
}
static __device__ __forceinline__ float bf16_to_f(unsigned short s){
  return __uint_as_float(((unsigned int)s) << 16);
}

__device__ __forceinline__ float sigf(float x){
  x = fminf(fmaxf(x, -30.f), 30.f);
  return 1.f/(1.f + __expf(-x));
}
__device__ __forceinline__ float tanhf_(float x){
  x = fminf(fmaxf(x, -15.f), 15.f);
  float e = __expf(2.f*x);
  return (e - 1.f)/(e + 1.f);
}

// Pack W into MFMA-B-fragment order, split into bf16 hi/lo.
//  effective (internal): we[g][k] = W[g][k] + 0.5*W[g][128+k]
//  leaf:                 wl[g][k] = W[g][128+k]
// Pack index: (((w*8 + gl)*4 + kc)*64 + lane)*8 + j
//   gl = q*2 + ft;  g = q*128 + w*32 + ft*16 + (lane&15)
//   k  = kc*32 + (lane>>4)*8 + j        (same k-map as A fragments)
__global__ __launch_bounds__(NT) void prep_pack(
    const float* __restrict__ W,
    unsigned short* __restrict__ pEh, unsigned short* __restrict__ pEl,
    unsigned short* __restrict__ pLh, unsigned short* __restrict__ pLl)
{
  int idx = blockIdx.x*NT + threadIdx.x;     // 0..8191
  int l  = idx & 63;
  int kc = (idx >> 6) & 3;
  int gl = (idx >> 8) & 7;
  int w  = (idx >> 11);                      // 0..3
  int q  = gl >> 1, ft = gl & 1;
  int g  = q*128 + w*32 + ft*16 + (l & 15);
  int kbase = kc*32 + (l >> 4)*8;

  unsigned short eh[8], el[8], lh[8], ll[8];
#pragma unroll
  for (int j = 0; j < 8; ++j){
    int k = kbase + j;
    float w0 = W[g*256 + k];
    float w1 = W[g*256 + 128 + k];
    float we = w0 + 0.5f*w1;
    unsigned short h0 = bf16_rne(we);
    eh[j] = h0; el[j] = bf16_rne(we - bf16_to_f(h0));
    unsigned short h1 = bf16_rne(w1);
    lh[j] = h1; ll[j] = bf16_rne(w1 - bf16_to_f(h1));
  }
  long base = (long)idx*8;
  *(bf16x8*)&pEh[base] = *(bf16x8*)eh;
  *(bf16x8*)&pEl[base] = *(bf16x8*)el;
  *(bf16x8*)&pLh[base] = *(bf16x8*)lh;
  *(bf16x8*)&pLl[base] = *(bf16x8*)ll;
}

// One tree level via MFMA. Block: 32 nodes x 512 gates, 4 waves.
// Wave w owns features [w*32, w*32+32) x all 4 gate types (8 D-tiles of 16x16).
template<int LEAF>
__global__ __launch_bounds__(NT) void level_mfma(
    const float* __restrict__ h_prev, const float* __restrict__ c_prev,
    const float* __restrict__ x_leaf,
    const unsigned short* __restrict__ packH, const unsigned short* __restrict__ packL,
    const float* __restrict__ bias,
    float* __restrict__ h_out, float* __restrict__ c_out, int N)
{
  __shared__ unsigned short AsH[BN][HH+8];   // A hi, padded (272B rows, 16B-aligned)
  __shared__ unsigned short AsL[BN][HH+8];   // A lo

  const int t = threadIdx.x;

  // ---- stage A (split to bf16 hi/lo) ----
  {
    int row = t >> 3;            // 0..31
    int ks  = (t & 7) * 16;      // 16 floats per thread
    int J   = blockIdx.x*BN + row;
    float v[16];
    if (J < N){
      if (LEAF){
#pragma unroll
        for (int i4 = 0; i4 < 4; ++i4)
          *(float4*)&v[i4*4] = *(const float4*)&x_leaf[(long)J*HH + ks + i4*4];
      } else {
        float a[16], b[16];
#pragma unroll
        for (int i4 = 0; i4 < 4; ++i4){
          *(float4*)&a[i4*4] = *(const float4*)&h_prev[(long)(2*J)*HH + ks + i4*4];
          *(float4*)&b[i4*4] = *(const float4*)&h_prev[(long)(2*J+1)*HH + ks + i4*4];
        }
#pragma unroll
        for (int i = 0; i < 16; ++i) v[i] = a[i] + b[i];
      }
    } else {
#pragma unroll
      for (int i = 0; i < 16; ++i) v[i] = 0.f;
    }
    unsigned short hh[16], ll[16];
#pragma unroll
    for (int i = 0; i < 16; ++i){
      unsigned short h0 = bf16_rne(v[i]);
      hh[i] = h0;
      ll[i] = bf16_rne(v[i] - bf16_to_f(h0));
    }
    *(bf16x8*)&AsH[row][ks]   = *(bf16x8*)&hh[0];
    *(bf16x8*)&AsH[row][ks+8] = *(bf16x8*)&hh[8];
    *(bf16x8*)&AsL[row][ks]   = *(bf16x8*)&ll[0];
    *(bf16x8*)&AsL[row][ks+8] = *(bf16x8*)&ll[8];
  }
  __syncthreads();

  const int w = t >> 6, l = t & 63;

  f32x4 acc[2][8];
#pragma unroll
  for (int mt = 0; mt < 2; ++mt)
#pragma unroll
    for (int gl = 0; gl < 8; ++gl) acc[mt][gl] = (f32x4)(0.f);

#pragma unroll
  for (int kc = 0; kc < 4; ++kc){
    bf16x8 aH[2], aL[2];
#pragma unroll
    for (int mt = 0; mt < 2; ++mt){
      int row = mt*16 + (l & 15);
      int co  = kc*32 + (l >> 4)*8;
      aH[mt] = *(const bf16x8*)&AsH[row][co];
      aL[mt] = *(const bf16x8*)&AsL[row][co];
    }
#pragma unroll
    for (int gl = 0; gl < 8; ++gl){
      long off = ((long)((w*8 + gl)*4 + kc)*64 + l)*8;
      bf16x8 bH = *(const bf16x8*)&packH[off];
      bf16x8 bL = *(const bf16x8*)&packL[off];
#pragma unroll
      for (int mt = 0; mt < 2; ++mt){
        acc[mt][gl] = __builtin_amdgcn_mfma_f32_16x16x32_bf16(aH[mt], bH, acc[mt][gl], 0, 0, 0);
        acc[mt][gl] = __builtin_amdgcn_mfma_f32_16x16x32_bf16(aH[mt], bL, acc[mt][gl], 0, 0, 0);
        acc[mt][gl] = __builtin_amdgcn_mfma_f32_16x16x32_bf16(aL[mt], bH, acc[mt][gl], 0, 0, 0);
      }
    }
  }

  // ---- epilogue: LSTM cell, lane-local across gate types ----
  float B[8];
#pragma unroll
  for (int gl = 0; gl < 8; ++gl)
    B[gl] = bias[(gl>>1)*128 + w*32 + (gl&1)*16 + (l & 15)];

#pragma unroll
  for (int mt = 0; mt < 2; ++mt){
#pragma unroll
    for (int r = 0; r < 4; ++r){
      int node = mt*16 + (l >> 4)*4 + r;
      int J = blockIdx.x*BN + node;
      if (J >= N) continue;
#pragma unroll
      for (int ft = 0; ft < 2; ++ft){
        int feat = w*32 + ft*16 + (l & 15);
        float cc = 0.f;
        if (!LEAF)
          cc = c_prev[(long)(2*J)*HH + feat] + c_prev[(long)(2*J+1)*HH + feat];
        float fv = acc[mt][0+ft][r] + B[0+ft];
        float iv = acc[mt][2+ft][r] + B[2+ft];
        float gv = acc[mt][4+ft][r] + B[4+ft];
        float ov = acc[mt][6+ft][r] + B[6+ft];
        float c = sigf(fv)*cc + sigf(iv)*tanhf_(gv);
        float h = sigf(ov)*tanhf_(c);
        h_out[(long)J*HH + feat] = h;
        c_out[(long)J*HH + feat] = c;
      }
    }
  }
}

extern "C" void kernel_launch(void* const* d_in, const int* in_sizes, int n_in,
                              void* d_out, int out_size, void* d_ws, size_t ws_size,
                              hipStream_t stream){
  const float* leaf = (const float*)d_in[0];   // 131072 x 128 f32
  const float* W    = (const float*)d_in[1];   // 512 x 256 f32
  const float* bias = (const float*)d_in[2];   // 512 f32
  float* out = (float*)d_out;                  // 128 f32

  unsigned short* pEh = (unsigned short*)d_ws;         // 65536 each (128KB)
  unsigned short* pEl = pEh + 65536;
  unsigned short* pLh = pEl + 65536;
  unsigned short* pLl = pLh + 65536;
  float* hA = (float*)(pLl + 65536);           // 2^17 * 128
  float* cA = hA + (long)(1<<17)*HH;
  float* hB = cA + (long)(1<<17)*HH;           // 2^16 * 128
  float* cB = hB + (long)(1<<16)*HH;

  prep_pack<<<32, NT, 0, stream>>>(W, pEh, pEl, pLh, pLl);

  int N = 1<<17;
  level_mfma<1><<<N/BN, NT, 0, stream>>>(nullptr, nullptr, leaf, pLh, pLl, bias, hA, cA, N);

  float *hin=hA, *cin=cA, *hout=hB, *cout=cB;
  for (int lvl = 1; lvl <= 17; ++lvl){
    N >>= 1;
    float* ho = (N==1) ? out : hout;
    int grid = (N + BN - 1)/BN;
    level_mfma<0><<<grid, NT, 0, stream>>>(hin, cin, nullptr, pEh, pEl, bias, ho, cout, N);
    float* th=hin; hin=hout; hout=th;
    float* tc=cin; cin=cout; cout=tc;
  }
  (void)in_sizes; (void)n_in; (void)out_size; (void)ws_size;
}

// Round 3
// 267.143 us; speedup vs baseline: 3.4350x; 1.3342x over previous
//
#include <hip/hip_runtime.h>

#define HH 128
#define GG 512
#define BN 32
#define NT 256
#define CPAD 132   // fp32 LDS row stride for subtree buffers (16B aligned, 4-way max conflict)

typedef float  f32x4  __attribute__((ext_vector_type(4)));
typedef short  bf16x8 __attribute__((ext_vector_type(8)));

static __device__ __forceinline__ unsigned short bf16_rne(float f){
  unsigned int u = __float_as_uint(f);
  unsigned int r = u + 0x7fffu + ((u >> 16) & 1u);
  return (unsigned short)(r >> 16);
}
static __device__ __forceinline__ unsigned short bf16_trunc(float f){
  return (unsigned short)(__float_as_uint(f) >> 16);
}
static __device__ __forceinline__ float bf16_to_f(unsigned short s){
  return __uint_as_float(((unsigned int)s) << 16);
}

// fast saturating sigmoid/tanh via v_exp_f32 + v_rcp_f32 (handles +-inf correctly)
__device__ __forceinline__ float sigf(float x){
  float t = __builtin_amdgcn_exp2f(-1.44269504089f * x);
  return __builtin_amdgcn_rcpf(1.f + t);
}
__device__ __forceinline__ float tanhf_(float x){
  float t = __builtin_amdgcn_exp2f(2.88539008178f * x);
  return 1.f - 2.f*__builtin_amdgcn_rcpf(t + 1.f);
}

// Pack W into MFMA-B-fragment order, split into bf16 hi/lo.
//  effective (internal): we[g][k] = W[g][k] + 0.5*W[g][128+k]
//  leaf:                 wl[g][k] = W[g][128+k]
// Pack index: (((w*8 + gl)*4 + kc)*64 + lane)*8 + j
//   gl = q*2 + ft;  g = q*128 + w*32 + ft*16 + (lane&15)
//   k  = kc*32 + (lane>>4)*8 + j        (same k-map as A fragments)
__global__ __launch_bounds__(NT) void prep_pack(
    const float* __restrict__ W,
    unsigned short* __restrict__ pEh, unsigned short* __restrict__ pEl,
    unsigned short* __restrict__ pLh, unsigned short* __restrict__ pLl)
{
  int idx = blockIdx.x*NT + threadIdx.x;     // 0..8191
  int l  = idx & 63;
  int kc = (idx >> 6) & 3;
  int gl = (idx >> 8) & 7;
  int w  = (idx >> 11);                      // 0..3
  int q  = gl >> 1, ft = gl & 1;
  int g  = q*128 + w*32 + ft*16 + (l & 15);
  int kbase = kc*32 + (l >> 4)*8;

  unsigned short eh[8], el[8], lh[8], ll[8];
#pragma unroll
  for (int j = 0; j < 8; ++j){
    int k = kbase + j;
    float w0 = W[g*256 + k];
    float w1 = W[g*256 + 128 + k];
    float we = w0 + 0.5f*w1;
    unsigned short h0 = bf16_rne(we);
    eh[j] = h0; el[j] = bf16_trunc(we - bf16_to_f(h0));
    unsigned short h1 = bf16_rne(w1);
    lh[j] = h1; ll[j] = bf16_trunc(w1 - bf16_to_f(h1));
  }
  long base = (long)idx*8;
  *(bf16x8*)&pEh[base] = *(bf16x8*)eh;
  *(bf16x8*)&pEl[base] = *(bf16x8*)el;
  *(bf16x8*)&pLh[base] = *(bf16x8*)lh;
  *(bf16x8*)&pLl[base] = *(bf16x8*)ll;
}

// One tree level via MFMA. Block: 32 nodes x 512 gates, 4 waves.
// Wave w owns features [w*32, w*32+32) x all 4 gate types (8 D-tiles of 16x16).
template<int LEAF>
__global__ __launch_bounds__(NT) void level_mfma(
    const float* __restrict__ h_prev, const float* __restrict__ c_prev,
    const float* __restrict__ x_leaf,
    const unsigned short* __restrict__ packH, const unsigned short* __restrict__ packL,
    const float* __restrict__ bias,
    float* __restrict__ h_out, float* __restrict__ c_out, int N)
{
  __shared__ unsigned short AsH[BN][HH+8];   // A hi, padded (272B rows, 16B-aligned)
  __shared__ unsigned short AsL[BN][HH+8];   // A lo

  const int t = threadIdx.x;

  // ---- stage A (split to bf16 hi/lo) ----
  {
    int row = t >> 3;            // 0..31
    int ks  = (t & 7) * 16;      // 16 floats per thread
    int J   = blockIdx.x*BN + row;
    float v[16];
    if (J < N){
      if (LEAF){
#pragma unroll
        for (int i4 = 0; i4 < 4; ++i4)
          *(float4*)&v[i4*4] = *(const float4*)&x_leaf[(long)J*HH + ks + i4*4];
      } else {
        float a[16], b[16];
#pragma unroll
        for (int i4 = 0; i4 < 4; ++i4){
          *(float4*)&a[i4*4] = *(const float4*)&h_prev[(long)(2*J)*HH + ks + i4*4];
          *(float4*)&b[i4*4] = *(const float4*)&h_prev[(long)(2*J+1)*HH + ks + i4*4];
        }
#pragma unroll
        for (int i = 0; i < 16; ++i) v[i] = a[i] + b[i];
      }
    } else {
#pragma unroll
      for (int i = 0; i < 16; ++i) v[i] = 0.f;
    }
    unsigned short hh[16], ll[16];
#pragma unroll
    for (int i = 0; i < 16; ++i){
      unsigned short h0 = bf16_rne(v[i]);
      hh[i] = h0;
      ll[i] = bf16_trunc(v[i] - bf16_to_f(h0));
    }
    *(bf16x8*)&AsH[row][ks]   = *(bf16x8*)&hh[0];
    *(bf16x8*)&AsH[row][ks+8] = *(bf16x8*)&hh[8];
    *(bf16x8*)&AsL[row][ks]   = *(bf16x8*)&ll[0];
    *(bf16x8*)&AsL[row][ks+8] = *(bf16x8*)&ll[8];
  }
  __syncthreads();

  const int w = t >> 6, l = t & 63;

  f32x4 acc[2][8];
#pragma unroll
  for (int mt = 0; mt < 2; ++mt)
#pragma unroll
    for (int gl = 0; gl < 8; ++gl) acc[mt][gl] = (f32x4)(0.f);

#pragma unroll
  for (int kc = 0; kc < 4; ++kc){
    bf16x8 aH[2], aL[2];
#pragma unroll
    for (int mt = 0; mt < 2; ++mt){
      int row = mt*16 + (l & 15);
      int co  = kc*32 + (l >> 4)*8;
      aH[mt] = *(const bf16x8*)&AsH[row][co];
      aL[mt] = *(const bf16x8*)&AsL[row][co];
    }
#pragma unroll
    for (int gl = 0; gl < 8; ++gl){
      long off = ((long)((w*8 + gl)*4 + kc)*64 + l)*8;
      bf16x8 bH = *(const bf16x8*)&packH[off];
      bf16x8 bL = *(const bf16x8*)&packL[off];
#pragma unroll
      for (int mt = 0; mt < 2; ++mt){
        acc[mt][gl] = __builtin_amdgcn_mfma_f32_16x16x32_bf16(aH[mt], bH, acc[mt][gl], 0, 0, 0);
        acc[mt][gl] = __builtin_amdgcn_mfma_f32_16x16x32_bf16(aH[mt], bL, acc[mt][gl], 0, 0, 0);
        acc[mt][gl] = __builtin_amdgcn_mfma_f32_16x16x32_bf16(aL[mt], bH, acc[mt][gl], 0, 0, 0);
      }
    }
  }

  // ---- epilogue: LSTM cell, lane-local across gate types ----
  float B[8];
#pragma unroll
  for (int gl = 0; gl < 8; ++gl)
    B[gl] = bias[(gl>>1)*128 + w*32 + (gl&1)*16 + (l & 15)];

#pragma unroll
  for (int mt = 0; mt < 2; ++mt){
#pragma unroll
    for (int r = 0; r < 4; ++r){
      int node = mt*16 + (l >> 4)*4 + r;
      int J = blockIdx.x*BN + node;
      if (J >= N) continue;
#pragma unroll
      for (int ft = 0; ft < 2; ++ft){
        int feat = w*32 + ft*16 + (l & 15);
        float cc = 0.f;
        if (!LEAF)
          cc = c_prev[(long)(2*J)*HH + feat] + c_prev[(long)(2*J+1)*HH + feat];
        float fv = acc[mt][0+ft][r] + B[0+ft];
        float iv = acc[mt][2+ft][r] + B[2+ft];
        float gv = acc[mt][4+ft][r] + B[4+ft];
        float ov = acc[mt][6+ft][r] + B[6+ft];
        float c = sigf(fv)*cc + sigf(iv)*tanhf_(gv);
        float h = sigf(ov)*tanhf_(c);
        h_out[(long)J*HH + feat] = h;
        c_out[(long)J*HH + feat] = c;
      }
    }
  }
}

// Reduce 32 adjacent children -> 1 node entirely inside one block (5 levels,
// __syncthreads only). FINAL=1 writes the root h to root_out (128 floats).
template<int FINAL>
__global__ __launch_bounds__(NT) void subtree_mfma(
    const float* __restrict__ h_in, const float* __restrict__ c_in,
    float* __restrict__ h_out, float* __restrict__ c_out,
    const unsigned short* __restrict__ packH, const unsigned short* __restrict__ packL,
    const float* __restrict__ bias, float* __restrict__ root_out)
{
  __shared__ float chF[32][CPAD];   // child h (fp32)
  __shared__ float ccF[32][CPAD];   // child c (fp32)

  const int t = threadIdx.x;
  const long b = blockIdx.x;

  // stage 32 children from global
  {
    int row = t >> 3;
    int ks  = (t & 7)*16;
    long base = (b*32 + row)*(long)HH + ks;
#pragma unroll
    for (int i4 = 0; i4 < 4; ++i4){
      *(float4*)&chF[row][ks + i4*4] = *(const float4*)&h_in[base + i4*4];
      *(float4*)&ccF[row][ks + i4*4] = *(const float4*)&c_in[base + i4*4];
    }
  }
  __syncthreads();

  const int w = t >> 6, l = t & 63;
  const int r = l & 15;
  const int khalf = (l >> 4)*8;

  float B[8];
#pragma unroll
  for (int gl = 0; gl < 8; ++gl)
    B[gl] = bias[(gl>>1)*128 + w*32 + (gl&1)*16 + r];

  for (int lv = 0; lv < 5; ++lv){
    const int n_out = 16 >> lv;

    // ---- build A fragments in registers (A row r = child 2r + child 2r+1) ----
    bf16x8 aH[4], aL[4];
#pragma unroll
    for (int kc = 0; kc < 4; ++kc){
      int co = kc*32 + khalf;
      float s[8];
#pragma unroll
      for (int jj = 0; jj < 8; jj += 4){
        float4 x = *(float4*)&chF[2*r][co+jj];
        float4 y = *(float4*)&chF[2*r+1][co+jj];
        s[jj+0]=x.x+y.x; s[jj+1]=x.y+y.y; s[jj+2]=x.z+y.z; s[jj+3]=x.w+y.w;
      }
      unsigned short hh[8], ll[8];
#pragma unroll
      for (int j = 0; j < 8; ++j){
        unsigned short h0 = bf16_rne(s[j]);
        hh[j] = h0; ll[j] = bf16_trunc(s[j] - bf16_to_f(h0));
      }
      aH[kc] = *(bf16x8*)hh; aL[kc] = *(bf16x8*)ll;
    }

    // ---- 16-row MFMA tile ----
    f32x4 acc[8];
#pragma unroll
    for (int gl = 0; gl < 8; ++gl) acc[gl] = (f32x4)(0.f);
#pragma unroll
    for (int kc = 0; kc < 4; ++kc){
#pragma unroll
      for (int gl = 0; gl < 8; ++gl){
        long off = ((long)((w*8 + gl)*4 + kc)*64 + l)*8;
        bf16x8 bH = *(const bf16x8*)&packH[off];
        bf16x8 bL = *(const bf16x8*)&packL[off];
        acc[gl] = __builtin_amdgcn_mfma_f32_16x16x32_bf16(aH[kc], bH, acc[gl], 0, 0, 0);
        acc[gl] = __builtin_amdgcn_mfma_f32_16x16x32_bf16(aH[kc], bL, acc[gl], 0, 0, 0);
        acc[gl] = __builtin_amdgcn_mfma_f32_16x16x32_bf16(aL[kc], bH, acc[gl], 0, 0, 0);
      }
    }

    // ---- epilogue into registers ----
    float hv[4][2], cv[4][2];
#pragma unroll
    for (int rr = 0; rr < 4; ++rr){
      int J = (l >> 4)*4 + rr;
#pragma unroll
      for (int ft = 0; ft < 2; ++ft){
        int feat = w*32 + ft*16 + r;
        float cc = ccF[2*J][feat] + ccF[2*J+1][feat];
        float fv = acc[0+ft][rr] + B[0+ft];
        float iv = acc[2+ft][rr] + B[2+ft];
        float gv = acc[4+ft][rr] + B[4+ft];
        float ov = acc[6+ft][rr] + B[6+ft];
        float c = sigf(fv)*cc + sigf(iv)*tanhf_(gv);
        float h = sigf(ov)*tanhf_(c);
        hv[rr][ft] = h; cv[rr][ft] = c;
      }
    }
    __syncthreads();   // all reads of chF/ccF complete before overwrite

    if (lv < 4){
#pragma unroll
      for (int rr = 0; rr < 4; ++rr){
        int J = (l >> 4)*4 + rr;
        if (J < n_out){
#pragma unroll
          for (int ft = 0; ft < 2; ++ft){
            int feat = w*32 + ft*16 + r;
            chF[J][feat] = hv[rr][ft];
            ccF[J][feat] = cv[rr][ft];
          }
        }
      }
      __syncthreads();
    } else {
      // n_out == 1: lanes with J==0 (quarter-wave 0, rr==0) hold the root
      if ((l >> 4) == 0){
#pragma unroll
        for (int ft = 0; ft < 2; ++ft){
          int feat = w*32 + ft*16 + r;
          if (FINAL){
            root_out[feat] = hv[0][ft];
          } else {
            h_out[b*HH + feat] = hv[0][ft];
            c_out[b*HH + feat] = cv[0][ft];
          }
        }
      }
    }
  }
}

extern "C" void kernel_launch(void* const* d_in, const int* in_sizes, int n_in,
                              void* d_out, int out_size, void* d_ws, size_t ws_size,
                              hipStream_t stream){
  const float* leaf = (const float*)d_in[0];   // 131072 x 128 f32
  const float* W    = (const float*)d_in[1];   // 512 x 256 f32
  const float* bias = (const float*)d_in[2];   // 512 f32
  float* out = (float*)d_out;                  // 128 f32

  unsigned short* pEh = (unsigned short*)d_ws;         // 65536 each (128KB)
  unsigned short* pEl = pEh + 65536;
  unsigned short* pLh = pEl + 65536;
  unsigned short* pLl = pLh + 65536;
  float* hA = (float*)(pLl + 65536);           // 2^17 * 128
  float* cA = hA + (long)(1<<17)*HH;
  float* hB = cA + (long)(1<<17)*HH;           // 2^16 * 128
  float* cB = hB + (long)(1<<16)*HH;

  prep_pack<<<32, NT, 0, stream>>>(W, pEh, pEl, pLh, pLl);

  // big levels: full-parallel, one launch per level
  level_mfma<1><<<4096, NT, 0, stream>>>(nullptr, nullptr, leaf, pLh, pLl, bias, hA, cA, 1<<17);
  level_mfma<0><<<2048, NT, 0, stream>>>(hA, cA, nullptr, pEh, pEl, bias, hB, cB, 1<<16);
  level_mfma<0><<<1024, NT, 0, stream>>>(hB, cB, nullptr, pEh, pEl, bias, hA, cA, 1<<15);

  // tail: 32768 children -> 1 via 3 subtree launches (5 levels fused per launch)
  subtree_mfma<0><<<1024, NT, 0, stream>>>(hA, cA, hB, cB, pEh, pEl, bias, nullptr);
  subtree_mfma<0><<<32,   NT, 0, stream>>>(hB, cB, hA, cA, pEh, pEl, bias, nullptr);
  subtree_mfma<1><<<1,    NT, 0, stream>>>(hA, cA, nullptr, nullptr, pEh, pEl, bias, out);

  (void)in_sizes; (void)n_in; (void)out_size; (void)ws_size;
}

// Round 4
// 177.062 us; speedup vs baseline: 5.1826x; 1.5088x over previous
//
#include <hip/hip_runtime.h>

#define HH 128
#define NT 512
#define PT 256
#define G  256   // grid for level kernels (1 block/CU)

typedef float  f32x4  __attribute__((ext_vector_type(4)));
typedef short  bf16x8 __attribute__((ext_vector_type(8)));

static __device__ __forceinline__ unsigned short bf16_rne(float f){
  unsigned int u = __float_as_uint(f);
  unsigned int r = u + 0x7fffu + ((u >> 16) & 1u);
  return (unsigned short)(r >> 16);
}
static __device__ __forceinline__ unsigned short bf16_trunc(float f){
  return (unsigned short)(__float_as_uint(f) >> 16);
}
static __device__ __forceinline__ float bf16_to_f(unsigned short s){
  return __uint_as_float(((unsigned int)s) << 16);
}

// fast saturating sigmoid/tanh via v_exp_f32 + v_rcp_f32
__device__ __forceinline__ float sigf(float x){
  float t = __builtin_amdgcn_exp2f(-1.44269504089f * x);
  return __builtin_amdgcn_rcpf(1.f + t);
}
__device__ __forceinline__ float tanhf_(float x){
  float t = __builtin_amdgcn_exp2f(2.88539008178f * x);
  return 1.f - 2.f*__builtin_amdgcn_rcpf(t + 1.f);
}

// Pack W into MFMA-B-fragment order, split bf16 hi/lo.
// Pack index: (((wp*8 + q*2 + ft)*4 + kc)*64 + lane)*8 + j
//   g = q*128 + wp*32 + ft*16 + (lane&15);  k = kc*32 + (lane>>4)*8 + j
__global__ __launch_bounds__(PT) void prep_pack(
    const float* __restrict__ W,
    unsigned short* __restrict__ pEh, unsigned short* __restrict__ pEl,
    unsigned short* __restrict__ pLh, unsigned short* __restrict__ pLl)
{
  int idx = blockIdx.x*PT + threadIdx.x;     // 0..8191
  int l  = idx & 63;
  int kc = (idx >> 6) & 3;
  int gl = (idx >> 8) & 7;
  int wp = (idx >> 11);                      // 0..3
  int q  = gl >> 1, ft = gl & 1;
  int g  = q*128 + wp*32 + ft*16 + (l & 15);
  int kbase = kc*32 + (l >> 4)*8;

  unsigned short eh[8], el[8], lh[8], ll[8];
#pragma unroll
  for (int j = 0; j < 8; ++j){
    int k = kbase + j;
    float w0 = W[g*256 + k];
    float w1 = W[g*256 + 128 + k];
    float we = w0 + 0.5f*w1;
    unsigned short h0 = bf16_rne(we);
    eh[j] = h0; el[j] = bf16_trunc(we - bf16_to_f(h0));
    unsigned short h1 = bf16_rne(w1);
    lh[j] = h1; ll[j] = bf16_trunc(w1 - bf16_to_f(h1));
  }
  long base = (long)idx*8;
  *(bf16x8*)&pEh[base] = *(bf16x8*)eh;
  *(bf16x8*)&pEl[base] = *(bf16x8*)el;
  *(bf16x8*)&pLh[base] = *(bf16x8*)lh;
  *(bf16x8*)&pLl[base] = *(bf16x8*)ll;
}

// One tree level. 8 waves; wave w owns feats [w*16,w*16+16) x 4 gate types.
// B resident in 128 VGPRs per wave (loaded once). Grid-strides 32-row tiles,
// double-buffered LDS A (bf16 hi/lo).
template<int LEAF>
__global__ __launch_bounds__(NT, 2) void level_mfma(
    const float* __restrict__ h_prev, const float* __restrict__ c_prev,
    const float* __restrict__ x_leaf,
    const unsigned short* __restrict__ packH, const unsigned short* __restrict__ packL,
    const float* __restrict__ bias,
    float* __restrict__ h_out, float* __restrict__ c_out, int N)
{
  __shared__ unsigned short AsH[2][32][HH+8];
  __shared__ unsigned short AsL[2][32][HH+8];

  const int t = threadIdx.x;
  const int w = t >> 6, l = t & 63;

  // ---- resident B fragments: [q][kc], 128 VGPRs each of H/L ----
  bf16x8 rbH[4][4], rbL[4][4];
#pragma unroll
  for (int q = 0; q < 4; ++q)
#pragma unroll
    for (int kc = 0; kc < 4; ++kc){
      long off = ((long)((((w>>1)*8) + q*2 + (w&1))*4 + kc)*64 + l)*8;
      rbH[q][kc] = *(const bf16x8*)&packH[off];
      rbL[q][kc] = *(const bf16x8*)&packL[off];
    }

  float B4[4];
#pragma unroll
  for (int q = 0; q < 4; ++q) B4[q] = bias[q*128 + w*16 + (l & 15)];

  const int ntiles = N >> 5;

  auto stage = [&](int buf, int tile){
    int row = t >> 4;             // 0..31
    int ks  = (t & 15) * 8;       // 8 floats
    float v[8];
    if (LEAF){
      long base = ((long)(tile*32 + row))*HH + ks;
      *(float4*)&v[0] = *(const float4*)&x_leaf[base];
      *(float4*)&v[4] = *(const float4*)&x_leaf[base + 4];
    } else {
      long cbase = ((long)tile*64 + 2*row)*HH + ks;
      float a[8], b[8];
      *(float4*)&a[0] = *(const float4*)&h_prev[cbase];
      *(float4*)&a[4] = *(const float4*)&h_prev[cbase + 4];
      *(float4*)&b[0] = *(const float4*)&h_prev[cbase + HH];
      *(float4*)&b[4] = *(const float4*)&h_prev[cbase + HH + 4];
#pragma unroll
      for (int j = 0; j < 8; ++j) v[j] = a[j] + b[j];
    }
    unsigned short hh[8], ll[8];
#pragma unroll
    for (int j = 0; j < 8; ++j){
      unsigned short h0 = bf16_rne(v[j]);
      hh[j] = h0; ll[j] = bf16_trunc(v[j] - bf16_to_f(h0));
    }
    *(bf16x8*)&AsH[buf][row][ks] = *(bf16x8*)hh;
    *(bf16x8*)&AsL[buf][row][ks] = *(bf16x8*)ll;
  };

  int tile = blockIdx.x;
  if (tile < ntiles) stage(0, tile);
  __syncthreads();
  int buf = 0;

  for (; tile < ntiles; tile += G){
    int nxt = tile + G;
    if (nxt < ntiles) stage(buf^1, nxt);

    f32x4 acc[2][4];
#pragma unroll
    for (int mt = 0; mt < 2; ++mt)
#pragma unroll
      for (int q = 0; q < 4; ++q) acc[mt][q] = (f32x4)(0.f);

#pragma unroll
    for (int kc = 0; kc < 4; ++kc){
      bf16x8 aH[2], aL[2];
#pragma unroll
      for (int mt = 0; mt < 2; ++mt){
        int row = mt*16 + (l & 15);
        int co  = kc*32 + (l >> 4)*8;
        aH[mt] = *(const bf16x8*)&AsH[buf][row][co];
        aL[mt] = *(const bf16x8*)&AsL[buf][row][co];
      }
#pragma unroll
      for (int q = 0; q < 4; ++q){
#pragma unroll
        for (int mt = 0; mt < 2; ++mt){
          acc[mt][q] = __builtin_amdgcn_mfma_f32_16x16x32_bf16(aH[mt], rbH[q][kc], acc[mt][q], 0, 0, 0);
          acc[mt][q] = __builtin_amdgcn_mfma_f32_16x16x32_bf16(aH[mt], rbL[q][kc], acc[mt][q], 0, 0, 0);
          acc[mt][q] = __builtin_amdgcn_mfma_f32_16x16x32_bf16(aL[mt], rbH[q][kc], acc[mt][q], 0, 0, 0);
        }
      }
    }

    // epilogue
    int feat = w*16 + (l & 15);
#pragma unroll
    for (int mt = 0; mt < 2; ++mt){
#pragma unroll
      for (int rr = 0; rr < 4; ++rr){
        long node = (long)tile*32 + mt*16 + (l >> 4)*4 + rr;
        float cc = 0.f;
        if (!LEAF)
          cc = c_prev[(2*node)*HH + feat] + c_prev[(2*node+1)*HH + feat];
        float fv = acc[mt][0][rr] + B4[0];
        float iv = acc[mt][1][rr] + B4[1];
        float gv = acc[mt][2][rr] + B4[2];
        float ov = acc[mt][3][rr] + B4[3];
        float c = sigf(fv)*cc + sigf(iv)*tanhf_(gv);
        float h = sigf(ov)*tanhf_(c);
        h_out[node*HH + feat] = h;
        c_out[node*HH + feat] = c;
      }
    }
    __syncthreads();
    buf ^= 1;
  }
}

// Reduce (1<<LEVELS) adjacent children -> 1 node inside one block.
// Same wave/col mapping as level_mfma; B resident, h/c children in fp32 LDS.
template<int LEVELS, int FINAL>
__global__ __launch_bounds__(NT, 2) void subtree_mfma(
    const float* __restrict__ h_in, const float* __restrict__ c_in,
    float* __restrict__ h_out, float* __restrict__ c_out,
    const unsigned short* __restrict__ packH, const unsigned short* __restrict__ packL,
    const float* __restrict__ bias, float* __restrict__ root_out)
{
  __shared__ float chF[32][HH+4];
  __shared__ float ccF[32][HH+4];

  const int t = threadIdx.x;
  const int w = t >> 6, l = t & 63;
  const int NCH = 1 << LEVELS;

  // stage children (zero-fill unused rows)
  {
    int row = t >> 4;
    int ks  = (t & 15)*8;
    if (row < NCH){
      long base = ((long)blockIdx.x*NCH + row)*HH + ks;
      *(float4*)&chF[row][ks]   = *(const float4*)&h_in[base];
      *(float4*)&chF[row][ks+4] = *(const float4*)&h_in[base+4];
      *(float4*)&ccF[row][ks]   = *(const float4*)&c_in[base];
      *(float4*)&ccF[row][ks+4] = *(const float4*)&c_in[base+4];
    } else {
      float4 z = {0.f,0.f,0.f,0.f};
      *(float4*)&chF[row][ks] = z; *(float4*)&chF[row][ks+4] = z;
      *(float4*)&ccF[row][ks] = z; *(float4*)&ccF[row][ks+4] = z;
    }
  }

  bf16x8 rbH[4][4], rbL[4][4];
#pragma unroll
  for (int q = 0; q < 4; ++q)
#pragma unroll
    for (int kc = 0; kc < 4; ++kc){
      long off = ((long)((((w>>1)*8) + q*2 + (w&1))*4 + kc)*64 + l)*8;
      rbH[q][kc] = *(const bf16x8*)&packH[off];
      rbL[q][kc] = *(const bf16x8*)&packL[off];
    }
  float B4[4];
#pragma unroll
  for (int q = 0; q < 4; ++q) B4[q] = bias[q*128 + w*16 + (l & 15)];

  const int r = l & 15;
  const int khalf = (l >> 4)*8;
  const int feat = w*16 + r;

  __syncthreads();

  for (int lv = 0; lv < LEVELS; ++lv){
    const int n_out = NCH >> (lv+1);

    // build A fragments (row r = child 2r + child 2r+1)
    bf16x8 aH[4], aL[4];
#pragma unroll
    for (int kc = 0; kc < 4; ++kc){
      int co = kc*32 + khalf;
      float s[8];
#pragma unroll
      for (int jj = 0; jj < 8; jj += 4){
        float4 x = *(float4*)&chF[2*r][co+jj];
        float4 y = *(float4*)&chF[2*r+1][co+jj];
        s[jj+0]=x.x+y.x; s[jj+1]=x.y+y.y; s[jj+2]=x.z+y.z; s[jj+3]=x.w+y.w;
      }
      unsigned short hh[8], ll[8];
#pragma unroll
      for (int j = 0; j < 8; ++j){
        unsigned short h0 = bf16_rne(s[j]);
        hh[j] = h0; ll[j] = bf16_trunc(s[j] - bf16_to_f(h0));
      }
      aH[kc] = *(bf16x8*)hh; aL[kc] = *(bf16x8*)ll;
    }

    f32x4 acc[4];
#pragma unroll
    for (int q = 0; q < 4; ++q) acc[q] = (f32x4)(0.f);
#pragma unroll
    for (int kc = 0; kc < 4; ++kc)
#pragma unroll
      for (int q = 0; q < 4; ++q){
        acc[q] = __builtin_amdgcn_mfma_f32_16x16x32_bf16(aH[kc], rbH[q][kc], acc[q], 0, 0, 0);
        acc[q] = __builtin_amdgcn_mfma_f32_16x16x32_bf16(aH[kc], rbL[q][kc], acc[q], 0, 0, 0);
        acc[q] = __builtin_amdgcn_mfma_f32_16x16x32_bf16(aL[kc], rbH[q][kc], acc[q], 0, 0, 0);
      }

    float hv[4], cv[4];
#pragma unroll
    for (int rr = 0; rr < 4; ++rr){
      int J = (l >> 4)*4 + rr;
      float cc = ccF[2*J][feat] + ccF[2*J+1][feat];
      float fv = acc[0][rr] + B4[0];
      float iv = acc[1][rr] + B4[1];
      float gv = acc[2][rr] + B4[2];
      float ov = acc[3][rr] + B4[3];
      float c = sigf(fv)*cc + sigf(iv)*tanhf_(gv);
      float h = sigf(ov)*tanhf_(c);
      hv[rr] = h; cv[rr] = c;
    }
    __syncthreads();

    if (lv < LEVELS-1){
#pragma unroll
      for (int rr = 0; rr < 4; ++rr){
        int J = (l >> 4)*4 + rr;
        if (J < n_out){ chF[J][feat] = hv[rr]; ccF[J][feat] = cv[rr]; }
      }
      __syncthreads();
    } else {
      if ((l >> 4) == 0){
        if (FINAL){
          root_out[feat] = hv[0];
        } else {
          h_out[(long)blockIdx.x*HH + feat] = hv[0];
          c_out[(long)blockIdx.x*HH + feat] = cv[0];
        }
      }
    }
  }
}

extern "C" void kernel_launch(void* const* d_in, const int* in_sizes, int n_in,
                              void* d_out, int out_size, void* d_ws, size_t ws_size,
                              hipStream_t stream){
  const float* leaf = (const float*)d_in[0];   // 131072 x 128 f32
  const float* W    = (const float*)d_in[1];   // 512 x 256 f32
  const float* bias = (const float*)d_in[2];   // 512 f32
  float* out = (float*)d_out;                  // 128 f32

  unsigned short* pEh = (unsigned short*)d_ws;         // 65536 each
  unsigned short* pEl = pEh + 65536;
  unsigned short* pLh = pEl + 65536;
  unsigned short* pLl = pLh + 65536;
  float* hA = (float*)(pLl + 65536);           // 2^17 * 128
  float* cA = hA + (long)(1<<17)*HH;
  float* hB = cA + (long)(1<<17)*HH;           // 2^16 * 128
  float* cB = hB + (long)(1<<16)*HH;

  prep_pack<<<32, PT, 0, stream>>>(W, pEh, pEl, pLh, pLl);

  // big levels, register-resident B, grid-stride
  level_mfma<1><<<G, NT, 0, stream>>>(nullptr, nullptr, leaf, pLh, pLl, bias, hA, cA, 1<<17);
  level_mfma<0><<<G, NT, 0, stream>>>(hA, cA, nullptr, pEh, pEl, bias, hB, cB, 1<<16);
  level_mfma<0><<<G, NT, 0, stream>>>(hB, cB, nullptr, pEh, pEl, bias, hA, cA, 1<<15);
  level_mfma<0><<<G, NT, 0, stream>>>(hA, cA, nullptr, pEh, pEl, bias, hB, cB, 1<<14);
  level_mfma<0><<<G, NT, 0, stream>>>(hB, cB, nullptr, pEh, pEl, bias, hA, cA, 1<<13);

  // tail: 8192 -> 256 -> 8 -> 1
  subtree_mfma<5,0><<<256, NT, 0, stream>>>(hA, cA, hB, cB, pEh, pEl, bias, nullptr);
  subtree_mfma<5,0><<<8,   NT, 0, stream>>>(hB, cB, hA, cA, pEh, pEl, bias, nullptr);
  subtree_mfma<3,1><<<1,   NT, 0, stream>>>(hA, cA, nullptr, nullptr, pEh, pEl, bias, out);

  (void)in_sizes; (void)n_in; (void)out_size; (void)ws_size;
}